// Round 3
// baseline (488.137 us; speedup 1.0000x reference)
//
#include <hip/hip_runtime.h>
#include <hip/hip_bf16.h>
#include <math.h>

#define NBLK 16
#define KD 32
#define NDIM 512        // NBLK*KD
#define INDIM 64
#define DT_C 0.05f
#define TAU_EPS_C 1e-6f
#define MROWS 16        // batch rows per tile (one MFMA M-tile)
#define WGSIZE 1024     // 16 waves; wave j handles block j
#define LSTRIDE 520     // bf16 elems/row; %8==0 keeps rows 16B-aligned for ds_read_b128

// Packed k-interleaved layout: within block j, value at original col (nt*16+l15)
// lives at position p = 2*l15 + nt. Lane's two outputs (nt=0,1) are adjacent ->
// single ds_write_b32. MFMA is invariant to a consistent k-permutation of A and B.

typedef __attribute__((ext_vector_type(8))) short bf16x8;   // MFMA A/B frag (4 VGPRs)
typedef __attribute__((ext_vector_type(4))) float f32x4;    // MFMA C/D frag

#define MFMA16(a, b, c) __builtin_amdgcn_mfma_f32_16x16x32_bf16((a), (b), (c), 0, 0, 0)

__device__ __forceinline__ float fast_tanh(float x){
    float e = __expf(2.0f * x);
    return 1.0f - 2.0f / (e + 1.0f);
}
__device__ __forceinline__ unsigned short f2bf(float f){
    __hip_bfloat16 h = __float2bfloat16(f);   // RNE
    return *reinterpret_cast<unsigned short*>(&h);
}
__device__ __forceinline__ float bf2f(unsigned short u){
    unsigned int x = ((unsigned int)u) << 16;
    return *reinterpret_cast<float*>(&x);
}
__device__ __forceinline__ unsigned int pack_bf2(float a, float b){
    return (unsigned int)f2bf(a) | ((unsigned int)f2bf(b) << 16);
}

// B-frag with permuted k: frag element i sits at position p=quad*8+i,
// which is original k = ((p&1)<<4) | (p>>1). B[k][n] = W[n][k].
__device__ __forceinline__ bf16x8 load_bfrag_perm(const float* __restrict__ W,
                                                  int l15, int quad, int nt){
    bf16x8 r;
    #pragma unroll
    for (int i = 0; i < 8; ++i){
        int p  = quad*8 + i;
        int kk = ((p & 1) << 4) | (p >> 1);
        r[i] = (short)f2bf(W[(size_t)(nt*16 + l15)*KD + kk]);
    }
    return r;
}

__global__ __launch_bounds__(WGSIZE, 8)
void ltcn_mfma_kernel(const float* __restrict__ y_in,
                      const float* __restrict__ u_t,
                      const float* __restrict__ W_in,
                      const float* __restrict__ b_in,
                      const float* __restrict__ W_fwd,
                      const float* __restrict__ b_fwd,
                      const float* __restrict__ W_rec,
                      const float* __restrict__ b_rec,
                      const float* __restrict__ E_l,
                      const float* __restrict__ E_l_r,
                      const float* __restrict__ tau_raw,
                      const int* __restrict__ n_steps_p,
                      float* __restrict__ y_out,
                      int batch)
{
    __shared__ __align__(16) unsigned short Ybuf[MROWS * LSTRIDE];
    __shared__ __align__(16) unsigned short NetO[MROWS * LSTRIDE];
    __shared__ __align__(16) unsigned short NetR[MROWS * LSTRIDE];
    __shared__ float WinT[INDIM * KD];      // WinT[i][l] = W_in[l][i]
    __shared__ float Ubuf[MROWS][INDIM];

    const int tid  = threadIdx.x;
    const int j    = tid >> 6;       // wave id = block index 0..15
    const int lane = tid & 63;
    const int quad = lane >> 4;      // 0..3
    const int l15  = lane & 15;
    const int ns   = n_steps_p[0];

    // ---- once per WG: stage WinT; load weight B-frags + per-lane scalars ----
    for (int idx = tid; idx < KD * INDIM; idx += WGSIZE){
        int l = idx >> 6;            // W_in row (0..31)
        int i = idx & 63;            // W_in col (0..63)
        WinT[i*KD + l] = W_in[idx];
    }

    const float* Wr = W_rec  + (size_t)j * KD * KD;
    const float* Wf = W_fwd  + (size_t)((j > 0) ? (j-1) : 0) * KD * KD;
    const float* Ee = E_l    + (size_t)j * KD * KD;
    const float* Er = E_l_r  + (size_t)j * KD * KD;

    bf16x8 Brec[2], Bfwd[2], BEl[2], BElr[2];
    float brec_s[2], bfwd_s[2], invtau_s[2];
    #pragma unroll
    for (int nt = 0; nt < 2; ++nt){
        Brec[nt] = load_bfrag_perm(Wr, l15, quad, nt);
        Bfwd[nt] = load_bfrag_perm(Wf, l15, quad, nt);
        BEl[nt]  = load_bfrag_perm(Ee, l15, quad, nt);
        BElr[nt] = load_bfrag_perm(Er, l15, quad, nt);
        int l = nt*16 + l15;
        brec_s[nt] = b_rec[j*KD + l];
        bfwd_s[nt] = (j > 0) ? b_fwd[(j-1)*KD + l] : 0.f;
        float tr = tau_raw[j*KD + l];
        float sp = fmaxf(tr, 0.f) + log1pf(__expf(-fabsf(tr)));
        invtau_s[nt] = 1.0f / (sp + TAU_EPS_C);
    }
    const float bin_s = b_in[tid & (KD-1)];

    const int tiles = batch / MROWS;
    const f32x4 zero = {0.f, 0.f, 0.f, 0.f};
    // packed-word base offsets (uint index into the b16 buffers)
    const int wrow_base = j*16 + l15;             // word offset within a row for writes
    const int arow_off  = l15*LSTRIDE + j*KD;     // b16 offset of A-frag row start

    for (int t = blockIdx.x; t < tiles; t += gridDim.x){
        const int row0 = t * MROWS;

        // ---- load y (fp32 at D positions) + packed bf16 copy into Ybuf ----
        float yv[2][4];
        #pragma unroll
        for (int r = 0; r < 4; ++r){
            int rr = quad*4 + r;
            float v0 = y_in[(size_t)(row0 + rr)*NDIM + j*KD + l15];
            float v1 = y_in[(size_t)(row0 + rr)*NDIM + j*KD + 16 + l15];
            yv[0][r] = v0; yv[1][r] = v1;
            reinterpret_cast<unsigned int*>(Ybuf)[rr*(LSTRIDE/2) + wrow_base] = pack_bf2(v0, v1);
        }
        for (int idx = tid; idx < MROWS*INDIM; idx += WGSIZE)
            (&Ubuf[0][0])[idx] = u_t[(size_t)row0*INDIM + idx];
        __syncthreads();

        // ---- net0 (step-invariant): 512 threads, one 64-dot each ----
        if (tid < MROWS * KD){
            int b = tid >> 5;
            int l = tid & (KD-1);
            const float* ur = &Ubuf[b][0];
            float a0 = 0.f, a1 = 0.f;
            #pragma unroll
            for (int i = 0; i < INDIM; i += 2){
                a0 = fmaf(ur[i],   WinT[i*KD + l],     a0);
                a1 = fmaf(ur[i+1], WinT[(i+1)*KD + l], a1);
            }
            float n0 = fast_tanh(a0 + a1 + bin_s);
            // permuted position within block 0
            NetO[b*LSTRIDE + 2*(l & 15) + (l >> 4)] = f2bf(n0);  // persists all steps
        }
        __syncthreads();

        float decay[2][4];

        for (int s = 0; s < ns; ++s){
            // ================= phase A: nets =================
            if (j == 0){
                // net0 invariant: read |.| at D positions (one packed word per r)
                #pragma unroll
                for (int r = 0; r < 4; ++r){
                    unsigned int w = reinterpret_cast<const unsigned int*>(NetO)
                                        [(quad*4 + r)*(LSTRIDE/2) + l15];
                    decay[0][r] = fabsf(bf2f((unsigned short)(w & 0xFFFF)));
                    decay[1][r] = fabsf(bf2f((unsigned short)(w >> 16)));
                }
            } else {
                const bf16x8 Af = *reinterpret_cast<const bf16x8*>(
                    &Ybuf[arow_off - KD + quad*8]);         // block j-1
                f32x4 aF0 = MFMA16(Af, Bfwd[0], zero);
                f32x4 aF1 = MFMA16(Af, Bfwd[1], zero);
                #pragma unroll
                for (int r = 0; r < 4; ++r){
                    float nf0 = fast_tanh(aF0[r] + bfwd_s[0]);
                    float nf1 = fast_tanh(aF1[r] + bfwd_s[1]);
                    decay[0][r] = fabsf(nf0);
                    decay[1][r] = fabsf(nf1);
                    reinterpret_cast<unsigned int*>(NetO)
                        [(quad*4 + r)*(LSTRIDE/2) + wrow_base] = pack_bf2(nf0, nf1);
                }
            }
            {
                const bf16x8 Ar = *reinterpret_cast<const bf16x8*>(
                    &Ybuf[arow_off + quad*8]);              // block j
                f32x4 aR0 = MFMA16(Ar, Brec[0], zero);
                f32x4 aR1 = MFMA16(Ar, Brec[1], zero);
                #pragma unroll
                for (int r = 0; r < 4; ++r){
                    float nr0 = fast_tanh(aR0[r] + brec_s[0]);
                    float nr1 = fast_tanh(aR1[r] + brec_s[1]);
                    decay[0][r] += fabsf(nr0);
                    decay[1][r] += fabsf(nr1);
                    reinterpret_cast<unsigned int*>(NetR)
                        [(quad*4 + r)*(LSTRIDE/2) + wrow_base] = pack_bf2(nr0, nr1);
                }
            }
            __syncthreads();   // B1: nets visible, all Ybuf reads done

            // ================= phase B: projections + update =================
            {
                const bf16x8 AO = *reinterpret_cast<const bf16x8*>(&NetO[arow_off + quad*8]);
                const bf16x8 AR = *reinterpret_cast<const bf16x8*>(&NetR[arow_off + quad*8]);
                f32x4 acc0 = MFMA16(AR, BElr[0], zero);
                acc0 = MFMA16(AO, BEl[0], acc0);
                f32x4 acc1 = MFMA16(AR, BElr[1], zero);
                acc1 = MFMA16(AO, BEl[1], acc1);
                #pragma unroll
                for (int r = 0; r < 4; ++r){
                    float y0 = yv[0][r], y1 = yv[1][r];
                    float yn0 = fmaf(DT_C, fmaf(-y0, invtau_s[0] + decay[0][r], acc0[r]), y0);
                    float yn1 = fmaf(DT_C, fmaf(-y1, invtau_s[1] + decay[1][r], acc1[r]), y1);
                    yv[0][r] = yn0; yv[1][r] = yn1;
                    reinterpret_cast<unsigned int*>(Ybuf)
                        [(quad*4 + r)*(LSTRIDE/2) + wrow_base] = pack_bf2(yn0, yn1);
                }
            }
            __syncthreads();   // B2: new y visible, net reads done
        }

        // ---- store y (fp32 from registers) ----
        #pragma unroll
        for (int r = 0; r < 4; ++r){
            y_out[(size_t)(row0 + quad*4 + r)*NDIM + j*KD + l15]      = yv[0][r];
            y_out[(size_t)(row0 + quad*4 + r)*NDIM + j*KD + 16 + l15] = yv[1][r];
        }
    }
}

extern "C" void kernel_launch(void* const* d_in, const int* in_sizes, int n_in,
                              void* d_out, int out_size, void* d_ws, size_t ws_size,
                              hipStream_t stream) {
    const float* y       = (const float*)d_in[0];
    const float* u_t     = (const float*)d_in[1];
    const float* W_in    = (const float*)d_in[2];
    const float* b_in    = (const float*)d_in[3];
    const float* W_fwd   = (const float*)d_in[4];
    const float* b_fwd   = (const float*)d_in[5];
    const float* W_rec   = (const float*)d_in[6];
    const float* b_rec   = (const float*)d_in[7];
    const float* E_l     = (const float*)d_in[8];
    const float* E_l_r   = (const float*)d_in[9];
    const float* tau_raw = (const float*)d_in[10];
    const int*   n_steps = (const int*)d_in[11];
    float* out = (float*)d_out;

    const int batch = in_sizes[0] / NDIM;
    const int grid  = 512;   // 2 WGs/CU: barrier drains of one WG overlap the other's compute

    hipLaunchKernelGGL(ltcn_mfma_kernel, dim3(grid), dim3(WGSIZE), 0, stream,
                       y, u_t, W_in, b_in, W_fwd, b_fwd, W_rec, b_rec,
                       E_l, E_l_r, tau_raw, n_steps, out, batch);
}

// Round 4
// 338.955 us; speedup vs baseline: 1.4401x; 1.4401x over previous
//
#include <hip/hip_runtime.h>
#include <hip/hip_bf16.h>
#include <math.h>

#define NBLK 16
#define KD 32
#define NDIM 512        // NBLK*KD
#define INDIM 64
#define DT_C 0.05f
#define TAU_EPS_C 1e-6f
#define MROWS 16        // batch rows per tile
#define WGSIZE 1024     // 16 waves; wave j owns block j
#define LSTRIDE 520     // bf16 elems per row (16B-aligned rows)
#define WSTRIDE 260     // word (u32) stride

// Packed k-interleaved layout (as round 3): value at original col nt*16+l15
// sits at position p = 2*l15+nt; B-frags use the same k-permutation.

typedef __attribute__((ext_vector_type(8))) short bf16x8;
typedef __attribute__((ext_vector_type(4))) float f32x4;

#define MFMA16(a,b,c) __builtin_amdgcn_mfma_f32_16x16x32_bf16((a),(b),(c),0,0,0)

__device__ __forceinline__ float fast_tanh(float x){
    float e = __expf(2.0f * x);
    return 1.0f - 2.0f / (e + 1.0f);
}
__device__ __forceinline__ float bf2f(unsigned short u){
    unsigned int x = ((unsigned int)u) << 16;
    return *reinterpret_cast<float*>(&x);
}
// cheap pack: round-half-away (<=0.5 ulp) + byte-perm; 3 VALU inst total
__device__ __forceinline__ unsigned int pack_bf2_fast(float a, float b){
    unsigned int ua = __float_as_uint(a) + 0x8000u;
    unsigned int ub = __float_as_uint(b) + 0x8000u;
    // result: lo16 = a.hi16, hi16 = b.hi16
    return __builtin_amdgcn_perm(ua, ub, 0x03020706);
}
__device__ __forceinline__ unsigned short f2bf_rha(float f){
    return (unsigned short)((__float_as_uint(f) + 0x8000u) >> 16);
}
__device__ __forceinline__ unsigned short f2bf(float f){
    __hip_bfloat16 h = __float2bfloat16(f);   // RNE (setup paths only)
    return *reinterpret_cast<unsigned short*>(&h);
}

// B-frag with permuted k: frag elem i at pos p=quad*8+i -> original k=((p&1)<<4)|(p>>1)
__device__ __forceinline__ bf16x8 load_bfrag_perm(const float* __restrict__ W,
                                                  int l15, int quad, int nt){
    bf16x8 r;
    #pragma unroll
    for (int i = 0; i < 8; ++i){
        int p  = quad*8 + i;
        int kk = ((p & 1) << 4) | (p >> 1);
        r[i] = (short)f2bf(W[(size_t)(nt*16 + l15)*KD + kk]);
    }
    return r;
}

__global__ __launch_bounds__(WGSIZE, 4)
void ltcn_mfma_kernel(const float* __restrict__ y_in,
                      const float* __restrict__ u_t,
                      const float* __restrict__ W_in,
                      const float* __restrict__ b_in,
                      const float* __restrict__ W_fwd,
                      const float* __restrict__ b_fwd,
                      const float* __restrict__ W_rec,
                      const float* __restrict__ b_rec,
                      const float* __restrict__ E_l,
                      const float* __restrict__ E_l_r,
                      const float* __restrict__ tau_raw,
                      const int* __restrict__ n_steps_p,
                      float* __restrict__ y_out,
                      int batch)
{
    __shared__ __align__(16) unsigned short Ybuf0[MROWS * LSTRIDE];
    __shared__ __align__(16) unsigned short Ybuf1[MROWS * LSTRIDE];
    __shared__ __align__(16) char NetRaw[MROWS * LSTRIDE * 2];  // Net; pre-loop: WinT+Ubuf alias

    unsigned short* Net  = (unsigned short*)NetRaw;
    unsigned int*   NetW = (unsigned int*)NetRaw;
    float*          WinT = (float*)NetRaw;              // 8 KB  [i][l]
    float*          Ubuf = (float*)(NetRaw + 8192);     // 4 KB  [b][i]

    const int tid  = threadIdx.x;
    const int j    = tid >> 6;
    const int lane = tid & 63;
    const int quad = lane >> 4;
    const int l15  = lane & 15;
    const int ns   = n_steps_p[0];

    const float* Wr = W_rec + (size_t)j * KD * KD;
    const float* Wf = W_fwd + (size_t)((j > 0) ? (j-1) : 0) * KD * KD;
    const float* Ee = E_l   + (size_t)j * KD * KD;
    const float* Er = E_l_r + (size_t)j * KD * KD;

    bf16x8 Brec[2], Bfwd[2], BEl[2], BElr[2];
    f32x4  cinitR[2], cinitF[2];
    float  invtau2[2];
    #pragma unroll
    for (int nt = 0; nt < 2; ++nt){
        Brec[nt] = load_bfrag_perm(Wr, l15, quad, nt);
        Bfwd[nt] = load_bfrag_perm(Wf, l15, quad, nt);
        BEl[nt]  = load_bfrag_perm(Ee, l15, quad, nt);
        BElr[nt] = load_bfrag_perm(Er, l15, quad, nt);
        int l = nt*16 + l15;
        float br = b_rec[j*KD + l];
        float bf = (j > 0) ? b_fwd[(j-1)*KD + l] : 0.f;
        cinitR[nt] = (f32x4){br, br, br, br};
        cinitF[nt] = (f32x4){bf, bf, bf, bf};
        float tr = tau_raw[j*KD + l];
        float sp = fmaxf(tr, 0.f) + log1pf(__expf(-fabsf(tr)));
        invtau2[nt] = 1.0f / (sp + TAU_EPS_C);
    }
    const float bin_s = b_in[tid & (KD-1)];
    const f32x4 zero = {0.f, 0.f, 0.f, 0.f};

    const int tiles = batch / MROWS;
    const int wword = j*16 + l15;               // D-pos word col within a row
    const int aoff  = l15*LSTRIDE + j*KD;       // A-frag b16 row base

    for (int t = blockIdx.x; t < tiles; t += gridDim.x){
        const int row0 = t * MROWS;

        // ---- load y -> regs (fp32, D positions) + packed bf16 into Ybuf0 ----
        float yv[2][4];
        #pragma unroll
        for (int r = 0; r < 4; ++r){
            int rr = quad*4 + r;
            const float* yr = y_in + (size_t)(row0 + rr)*NDIM + j*KD;
            float v0 = yr[l15], v1 = yr[16 + l15];
            yv[0][r] = v0; yv[1][r] = v1;
            ((unsigned int*)Ybuf0)[rr*WSTRIDE + wword] = pack_bf2_fast(v0, v1);
        }
        // ---- stage WinT + Ubuf (aliased into Net region) ----
        for (int idx = tid; idx < KD*INDIM; idx += WGSIZE){
            int l = idx >> 6, i = idx & 63;
            WinT[i*KD + l] = W_in[idx];
        }
        for (int idx = tid; idx < MROWS*INDIM; idx += WGSIZE)
            Ubuf[idx] = u_t[(size_t)row0*INDIM + idx];
        __syncthreads();   // BAR1: staging + Ybuf0 visible

        // ---- net0 (step-invariant) -> Ybuf1 block-0 cols, packed D-pos ----
        if (tid < MROWS * KD){
            int b = tid >> 5, l = tid & 31;
            const float* ur = &Ubuf[b*INDIM];
            float a0 = 0.f, a1 = 0.f;
            #pragma unroll
            for (int i = 0; i < INDIM; i += 2){
                a0 = fmaf(ur[i],   WinT[i*KD + l],     a0);
                a1 = fmaf(ur[i+1], WinT[(i+1)*KD + l], a1);
            }
            float n0 = fast_tanh(a0 + a1 + bin_s);
            Ybuf1[b*LSTRIDE + 2*(l & 15) + (l >> 4)] = f2bf_rha(n0);
        }
        __syncthreads();   // BAR2: net0 visible; Net region now free for step use

        // wave 0 extracts its step-invariant state
        bf16x8 AO0 = {0,0,0,0,0,0,0,0};
        float base0[2][4];
        if (j == 0){
            AO0 = *(const bf16x8*)&Ybuf1[l15*LSTRIDE + quad*8];
            #pragma unroll
            for (int r = 0; r < 4; ++r){
                unsigned int w = ((const unsigned int*)Ybuf1)[(quad*4 + r)*WSTRIDE + l15];
                base0[0][r] = invtau2[0] + fabsf(bf2f((unsigned short)(w & 0xFFFF)));
                base0[1][r] = invtau2[1] + fabsf(bf2f((unsigned short)(w >> 16)));
            }
        }

        int cur = 0;
        for (int s = 0; s < ns; ++s){
            const unsigned short* Yr  = cur ? Ybuf1 : Ybuf0;
            unsigned int*         YwW = (unsigned int*)(cur ? Ybuf0 : Ybuf1);

            // ---- phase A: nets (reads Yr only) ----
            bf16x8 Ar = *(const bf16x8*)&Yr[aoff + quad*8];
            f32x4 aR0 = MFMA16(Ar, Brec[0], cinitR[0]);
            f32x4 aR1 = MFMA16(Ar, Brec[1], cinitR[1]);

            float d[2][4];
            bf16x8 AOf;
            if (j > 0){
                bf16x8 Af = *(const bf16x8*)&Yr[aoff - KD + quad*8];
                f32x4 aF0 = MFMA16(Af, Bfwd[0], cinitF[0]);
                f32x4 aF1 = MFMA16(Af, Bfwd[1], cinitF[1]);
                #pragma unroll
                for (int r = 0; r < 4; ++r){
                    float nf0 = fast_tanh(aF0[r]);
                    float nf1 = fast_tanh(aF1[r]);
                    d[0][r] = invtau2[0] + fabsf(nf0);
                    d[1][r] = invtau2[1] + fabsf(nf1);
                    NetW[(quad*4 + r)*WSTRIDE + wword] = pack_bf2_fast(nf0, nf1);
                }
                __builtin_amdgcn_wave_barrier();    // writes before read (same wave, in-order DS)
                AOf = *(const bf16x8*)&Net[aoff + quad*8];
                __builtin_amdgcn_wave_barrier();    // read before netR overwrite
            } else {
                #pragma unroll
                for (int r = 0; r < 4; ++r){ d[0][r] = base0[0][r]; d[1][r] = base0[1][r]; }
                AOf = AO0;
            }

            #pragma unroll
            for (int r = 0; r < 4; ++r){
                float nr0 = fast_tanh(aR0[r]);
                float nr1 = fast_tanh(aR1[r]);
                d[0][r] += fabsf(nr0);
                d[1][r] += fabsf(nr1);
                NetW[(quad*4 + r)*WSTRIDE + wword] = pack_bf2_fast(nr0, nr1);
            }
            __builtin_amdgcn_wave_barrier();
            bf16x8 ARf = *(const bf16x8*)&Net[aoff + quad*8];
            __builtin_amdgcn_wave_barrier();

            // ---- phase B: block-diagonal projections + update (intra-wave) ----
            f32x4 o0 = MFMA16(ARf, BElr[0], zero);
            o0 = MFMA16(AOf, BEl[0], o0);
            f32x4 o1 = MFMA16(ARf, BElr[1], zero);
            o1 = MFMA16(AOf, BEl[1], o1);

            const bool wr = (s + 1 < ns);
            #pragma unroll
            for (int r = 0; r < 4; ++r){
                float y0 = yv[0][r], y1 = yv[1][r];
                float yn0 = fmaf(DT_C, fmaf(-y0, d[0][r], o0[r]), y0);
                float yn1 = fmaf(DT_C, fmaf(-y1, d[1][r], o1[r]), y1);
                yv[0][r] = yn0; yv[1][r] = yn1;
                if (wr) YwW[(quad*4 + r)*WSTRIDE + wword] = pack_bf2_fast(yn0, yn1);
            }
            __syncthreads();   // the single per-step barrier: Yw visible for next step
            cur ^= 1;
        }

        // ---- store y from registers ----
        #pragma unroll
        for (int r = 0; r < 4; ++r){
            float* yo = y_out + (size_t)(row0 + quad*4 + r)*NDIM + j*KD;
            yo[l15]      = yv[0][r];
            yo[16 + l15] = yv[1][r];
        }
    }
}

extern "C" void kernel_launch(void* const* d_in, const int* in_sizes, int n_in,
                              void* d_out, int out_size, void* d_ws, size_t ws_size,
                              hipStream_t stream) {
    const float* y       = (const float*)d_in[0];
    const float* u_t     = (const float*)d_in[1];
    const float* W_in    = (const float*)d_in[2];
    const float* b_in    = (const float*)d_in[3];
    const float* W_fwd   = (const float*)d_in[4];
    const float* b_fwd   = (const float*)d_in[5];
    const float* W_rec   = (const float*)d_in[6];
    const float* b_rec   = (const float*)d_in[7];
    const float* E_l     = (const float*)d_in[8];
    const float* E_l_r   = (const float*)d_in[9];
    const float* tau_raw = (const float*)d_in[10];
    const int*   n_steps = (const int*)d_in[11];
    float* out = (float*)d_out;

    const int batch = in_sizes[0] / NDIM;
    const int grid  = 256;   // 1 WG/CU; 8 tiles per WG

    hipLaunchKernelGGL(ltcn_mfma_kernel, dim3(grid), dim3(WGSIZE), 0, stream,
                       y, u_t, W_in, b_in, W_fwd, b_fwd, W_rec, b_rec,
                       E_l, E_l_r, tau_raw, n_steps, out, batch);
}